// Round 7
// baseline (222.537 us; speedup 1.0000x reference)
//
#include <hip/hip_runtime.h>

typedef __attribute__((ext_vector_type(8))) short s16x8;
typedef __attribute__((ext_vector_type(4))) float f32x4;
typedef unsigned short u16;
typedef unsigned int   u32;

#define MFMA16(a,b,c) __builtin_amdgcn_mfma_f32_16x16x32_bf16((a),(b),(c),0,0,0)

__device__ __forceinline__ float bf2f(u16 u){
  u32 x = ((u32)u) << 16; float f; __builtin_memcpy(&f, &x, 4); return f;
}
__device__ __forceinline__ u16 f2bf(float f){
  u32 x; __builtin_memcpy(&x, &f, 4);
  x += 0x7FFFu + ((x >> 16) & 1u);   // round-to-nearest-even
  return (u16)(x >> 16);
}
#if defined(__has_builtin) && __has_builtin(__builtin_amdgcn_cvt_pk_bf16_f32)
__device__ __forceinline__ u32 pack2(float a, float b){
  return __builtin_bit_cast(u32, __builtin_amdgcn_cvt_pk_bf16_f32(a, b));
}
#else
__device__ __forceinline__ u32 pack2(float a, float b){
  return (u32)f2bf(a) | ((u32)f2bf(b) << 16);
}
#endif
#if defined(__has_builtin) && __has_builtin(__builtin_amdgcn_exp2f)
__device__ __forceinline__ float fexp2(float x){ return __builtin_amdgcn_exp2f(x); }
#else
extern "C" __device__ float __ocml_native_exp2_f32(float);
__device__ __forceinline__ float fexp2(float x){ return __ocml_native_exp2_f32(x); }
#endif

// w1_swz : [ntile=16][kc=22][lane=64][8]
//          B[k=kc*32+(lane>>4)*8+j][n=ntile*16+(lane&15)]  (zero-padded k>=676)

// ---------------------------------------------------------------------------
// wprep: once-per-launch W preparation.
// wp[l*4+h] is a [32 rows o][stride 40 f] bf16 tile:
//   rows 0..25 : W[l][h][f][o] transposed; row 26: W@a_src; row 27: W@a_dst;
//   rows 28..31 / cols >=26 : 0
// ---------------------------------------------------------------------------
__global__ __launch_bounds__(256) void wprep_kernel(
    const float* __restrict__ W, const float* __restrict__ a_src,
    const float* __restrict__ a_dst, u16* __restrict__ wp)
{
  const int lh = blockIdx.x;             // 0..11 = l*4+h
  const float* Wlh = W + lh*676;         // [f][o]
  u16* dst = wp + lh*32*40;
  const int t = threadIdx.x;
  for (int e = t; e < 1280; e += 256) dst[e] = 0;
  __syncthreads();
  for (int e = t; e < 676; e += 256){ int f = e/26, o = e%26; dst[o*40 + f] = f2bf(Wlh[f*26 + o]); }
  if (t < 52){
    int sel = t/26, f = t%26;
    const float* av = (sel ? a_dst : a_src) + lh*26;
    float acc = 0.f;
    #pragma unroll
    for (int o = 0; o < 26; ++o) acc += Wlh[f*26 + o]*av[o];
    dst[(26 + sel)*40 + f] = f2bf(acc);
  }
}

// ---------------------------------------------------------------------------
// W1 -> bf16 swizzled B-fragment layout w1_swz[ntile=16][kc=22][lane=64][8].
// ---------------------------------------------------------------------------
__global__ __launch_bounds__(256) void w1cvt_kernel(const float* __restrict__ W1,
                                                    u16* __restrict__ w1t)
{
  const int k = blockIdx.x * 2;            // 0..702 even
  const int n = threadIdx.x;
  float v0 = 0.f, v1 = 0.f;
  if (k < 676)     v0 = W1[(size_t)k*256 + n];
  if (k + 1 < 676) v1 = W1[(size_t)(k+1)*256 + n];
  const int ntile = n >> 4, lm = n & 15;
  const int kc = k >> 5, q16 = (k >> 3) & 3, j = k & 7;
  u16* dst = w1t + ((((size_t)ntile*22 + kc)*64 + q16*16 + lm) << 3) + j;
  *(u32*)dst = pack2(v0, v1);
}

// ---------------------------------------------------------------------------
// GAT kernel: 3 fused layers + FUSED MLP head. One block = 4 batch elements.
// Layers: round-6 body unchanged. Tail: x_final copied to xc (aliases dead
// hsT, stride 736 => 2-way LDS aliasing = free), then per-wave MFMA GEMM
// against w1_swz with A rows m = lane&3 (batches duplicated over M — dups
// land in D rows whose (q*4+r)&3 == r, so every reg r = batch r), fused
// +b1 / leaky / @W2 / shfl reduction, direct d_out write. No xf, no mlp krnl.
// ---------------------------------------------------------------------------
__global__ __launch_bounds__(256, 4) void gat_kernel(
    const float* __restrict__ x, const u16* __restrict__ wp,
    const u16* __restrict__ w1t, const float* __restrict__ b1,
    const float* __restrict__ w2, const float* __restrict__ b2,
    float* __restrict__ out)
{
  __shared__ __align__(16) u16 xs [112*40];
  __shared__ __align__(16) u16 hsT[4*32*108 + 16];
  __shared__ float part[4][4][3];

  const int tid  = threadIdx.x;
  const int w    = tid >> 6;
  const int lane = tid & 63;
  const int q    = lane >> 4;
  const int lm   = lane & 15;
  const int b0   = blockIdx.x * 4;
  const float L2E = 1.4426950408889634f;

  // zero hsT padding once (never written afterwards during the layer loop)
  for (int e = tid; e < 1728; e += 256){            // rows (o&31)>=28, all cols
    int r = e/108, c = e%108; int h = r>>2, rr = 28 + (r&3);
    hsT[(h*32 + rr)*108 + c] = 0;
  }
  for (int e = tid; e < 448; e += 256){             // cols 104..107, rows 0..27
    int r = e>>2, c = 104 + (e&3); int h = r/28, rr = r%28;
    hsT[(h*32 + rr)*108 + c] = 0;
  }
  if (tid < 16) hsT[4*32*108 + tid] = 0;
  // zero xs padding: cols 26..39 (all rows), rows 104..111 (cols 0..25)
  for (int e = tid; e < 112*14; e += 256){ int r = e/14, c = 26 + e%14; xs[r*40 + c] = 0; }
  for (int e = tid; e < 8*26;  e += 256){ int r = 104 + e/26, c = e%26; xs[r*40 + c] = 0; }
  // load x (fp32 pairs -> packed bf16)
  for (int pp = tid; pp < 1352; pp += 256){
    int b = pp/338, r2 = pp%338, n = r2/13, p = r2%13;
    float2 v = *(const float2*)&x[(b0 + b)*676 + n*26 + 2*p];
    *(u32*)&xs[(b*26 + n)*40 + 2*p] = pack2(v.x, v.y);
  }

  for (int l = 0; l < 3; ++l){
    __syncthreads();

    // ---- matmul1: h_aug = x @ W_aug  (head = w, W frags from global) ----
    {
      s16x8 bfr0 = *(const s16x8*)&wp[((l*4 + w)*32      + lm)*40 + q*8];
      s16x8 bfr1 = *(const s16x8*)&wp[((l*4 + w)*32 + 16 + lm)*40 + q*8];
      #pragma unroll
      for (int t = 0; t < 7; ++t){
        s16x8 af = *(const s16x8*)&xs[(t*16 + lm)*40 + q*8];
        f32x4 z = {0.f,0.f,0.f,0.f};
        f32x4 d0 = MFMA16(af, bfr0, z);
        f32x4 d1 = MFMA16(af, bfr1, z);
        int gr0 = t*16 + q*4;
        if (gr0 < 104){
          { uint2 uu; uu.x = pack2(d0[0], d0[1]); uu.y = pack2(d0[2], d0[3]);
            *(uint2*)&hsT[(w*32 + lm)*108 + gr0] = uu; }
          if (lm < 12){
            uint2 uu; uu.x = pack2(d1[0], d1[1]); uu.y = pack2(d1[2], d1[3]);
            *(uint2*)&hsT[(w*32 + 16 + lm)*108 + gr0] = uu; }
        }
      }
    }
    __syncthreads();

    // ---- matmul2: out^T = h^T @ alpha^T, softmax built in-register (bl = w)
    {
      f32x4 acc00 = {0,0,0,0}, acc01 = acc00, acc10 = acc00, acc11 = acc00;
      const int j0 = q*8;
      const int w26 = w*26;
      #pragma unroll
      for (int h = 0; h < 4; ++h){
        s16x8 am0, am1;
        {
          int base = (h*32 + lm)*108 + w26 + j0;
          uint4 uu = { *(const u32*)&hsT[base],   *(const u32*)&hsT[base+2],
                       *(const u32*)&hsT[base+4], *(const u32*)&hsT[base+6] };
          am0 = __builtin_bit_cast(s16x8, uu);
          base = (h*32 + 16 + lm)*108 + w26 + j0;
          uint4 vv = { *(const u32*)&hsT[base],   *(const u32*)&hsT[base+2],
                       *(const u32*)&hsT[base+4], *(const u32*)&hsT[base+6] };
          am1 = __builtin_bit_cast(s16x8, vv);
        }
        float sd2[8];
        {
          int base = (h*32 + 27)*108 + w26 + j0;
          #pragma unroll
          for (int u = 0; u < 4; ++u){
            u32 v = *(const u32*)&hsT[base + 2*u];
            sd2[2*u]   = bf2f((u16)(v & 0xFFFFu)) * L2E;
            sd2[2*u+1] = bf2f((u16)(v >> 16))     * L2E;
          }
          #pragma unroll
          for (int jj = 0; jj < 8; ++jj)
            if (j0 + jj >= 26) sd2[jj] = -1e30f;   // exp2 -> 0, kills j-pad
        }
        #pragma unroll
        for (int nt = 0; nt < 2; ++nt){
          int i = nt*16 + lm;
          float si2 = bf2f(hsT[(h*32 + 26)*108 + w26 + i]) * L2E;  // i>=26: junk, contained
          float p[8]; float loc = 0.f;
          #pragma unroll
          for (int jj = 0; jj < 8; ++jj){
            float e = si2 + sd2[jj];
            e = fmaxf(e, 0.2f*e);                  // leaky_relu (log2 domain)
            float pv = fexp2(e);
            p[jj] = pv; loc += pv;
          }
          float tot = loc;
          tot += __shfl_xor(tot, 16);
          tot += __shfl_xor(tot, 32);
          float rinv = __builtin_amdgcn_rcpf(tot);
          uint4 bu = { pack2(p[0]*rinv, p[1]*rinv), pack2(p[2]*rinv, p[3]*rinv),
                       pack2(p[4]*rinv, p[5]*rinv), pack2(p[6]*rinv, p[7]*rinv) };
          s16x8 bfrag = __builtin_bit_cast(s16x8, bu);
          if (nt == 0){ acc00 = MFMA16(am0, bfrag, acc00);
                        acc10 = MFMA16(am1, bfrag, acc10); }
          else        { acc01 = MFMA16(am0, bfrag, acc01);
                        acc11 = MFMA16(am1, bfrag, acc11); }
        }
      }
      // epilogue: mean heads (x0.25), ELU, write next-layer xs (bf16)
      #pragma unroll
      for (int nt = 0; nt < 2; ++nt){
        int i = nt*16 + lm;
        if (i < 26){
          int rowb = (w26 + i)*40;
          #pragma unroll
          for (int mt = 0; mt < 2; ++mt){
            f32x4 a = (mt == 0) ? (nt == 0 ? acc00 : acc01)
                                : (nt == 0 ? acc10 : acc11);
            int f0 = mt*16 + q*4;
            float v0 = a[0]*0.25f, v1 = a[1]*0.25f, v2 = a[2]*0.25f, v3 = a[3]*0.25f;
            v0 = (v0 > 0.f) ? v0 : (fexp2(v0*L2E) - 1.f);
            v1 = (v1 > 0.f) ? v1 : (fexp2(v1*L2E) - 1.f);
            v2 = (v2 > 0.f) ? v2 : (fexp2(v2*L2E) - 1.f);
            v3 = (v3 > 0.f) ? v3 : (fexp2(v3*L2E) - 1.f);
            if (f0 <= 20){
              uint2 uu; uu.x = pack2(v0, v1); uu.y = pack2(v2, v3);
              *(uint2*)&xs[rowb + f0] = uu;
            } else if (f0 == 24){
              *(u32*)&xs[rowb + 24] = pack2(v0, v1);
            }
          }
        }
      }
    }
  }

  // ---------------- fused MLP head ----------------
  // per-lane coefficients for cols n = w*64 + nt*16 + lm (issue early)
  float b1l[4], w2l[4][3];
  #pragma unroll
  for (int nt = 0; nt < 4; ++nt){
    int col = w*64 + nt*16 + lm;
    b1l[nt]    = b1[col];
    w2l[nt][0] = w2[col*3]; w2l[nt][1] = w2[col*3+1]; w2l[nt][2] = w2[col*3+2];
  }

  __syncthreads();                        // hsT reads done -> safe to alias
  u16* xc = hsT;                          // xc[4][736] flat bf16, k-padded 0
  for (int e = tid; e < 4*368; e += 256){ // u32 pairs, row stride 736
    int bb = e/368, p = e%368, k = 2*p;   // k even & 26 even => pair in-row
    u32 v = 0;
    if (k < 676){ int n = k/26, f = k - n*26; v = *(const u32*)&xs[(bb*26 + n)*40 + f]; }
    *(u32*)&xc[bb*736 + k] = v;
  }
  __syncthreads();

  {
    f32x4 acc[4];
    #pragma unroll
    for (int nt = 0; nt < 4; ++nt) acc[nt] = (f32x4){0.f,0.f,0.f,0.f};
    const int bb = lane & 3;              // A row m=lane&15 holds batch m&3
    const u16* bbase = w1t + (((size_t)w*4)*22*64 + lane)*8;
    #pragma unroll
    for (int kc = 0; kc < 22; ++kc){
      s16x8 afr = *(const s16x8*)&xc[bb*736 + kc*32 + q*8];
      #pragma unroll
      for (int nt = 0; nt < 4; ++nt){
        s16x8 bfr = *(const s16x8*)(bbase + (size_t)(nt*22 + kc)*64*8);
        acc[nt] = MFMA16(afr, bfr, acc[nt]);
      }
    }
    // D reg r = batch r (all q groups identical); fuse +b1, leaky, @W2
    float po[4][3];
    #pragma unroll
    for (int r = 0; r < 4; ++r){
      float s0 = 0.f, s1 = 0.f, s2 = 0.f;
      #pragma unroll
      for (int nt = 0; nt < 4; ++nt){
        float hv = acc[nt][r] + b1l[nt];
        hv = fmaxf(hv, 0.2f*hv);          // leaky_relu 0.2
        s0 += hv*w2l[nt][0]; s1 += hv*w2l[nt][1]; s2 += hv*w2l[nt][2];
      }
      po[r][0] = s0; po[r][1] = s1; po[r][2] = s2;
    }
    #pragma unroll
    for (int m = 1; m < 16; m <<= 1)
      #pragma unroll
      for (int r = 0; r < 4; ++r)
        #pragma unroll
        for (int kk = 0; kk < 3; ++kk)
          po[r][kk] += __shfl_xor(po[r][kk], m);
    if (lane == 0){
      #pragma unroll
      for (int r = 0; r < 4; ++r)
        #pragma unroll
        for (int kk = 0; kk < 3; ++kk)
          part[w][r][kk] = po[r][kk];
    }
  }
  __syncthreads();
  if (tid < 12){
    int r = tid/3, kk = tid - r*3;
    out[(b0 + r)*3 + kk] = part[0][r][kk] + part[1][r][kk]
                         + part[2][r][kk] + part[3][r][kk] + b2[kk];
  }
}

extern "C" void kernel_launch(void* const* d_in, const int* in_sizes, int n_in,
                              void* d_out, int out_size, void* d_ws, size_t ws_size,
                              hipStream_t stream)
{
  (void)in_sizes; (void)n_in; (void)out_size; (void)ws_size;
  const float* x     = (const float*)d_in[1];
  const float* W     = (const float*)d_in[2];
  const float* a_src = (const float*)d_in[3];
  const float* a_dst = (const float*)d_in[4];
  const float* W1    = (const float*)d_in[5];
  const float* b1    = (const float*)d_in[6];
  const float* W2    = (const float*)d_in[7];
  const float* b2    = (const float*)d_in[8];
  float* out = (float*)d_out;

  u16* w1t = (u16*)d_ws;                       // [16][22][64][8] bf16 (swz)
  u16* wp  = w1t + (size_t)16*22*64*8;         // [12][32][40]    bf16

  hipLaunchKernelGGL(wprep_kernel, dim3(12),   dim3(256), 0, stream, W, a_src, a_dst, wp);
  hipLaunchKernelGGL(w1cvt_kernel, dim3(352),  dim3(256), 0, stream, W1, w1t);
  hipLaunchKernelGGL(gat_kernel,   dim3(4096), dim3(256), 0, stream,
                     x, wp, w1t, b1, W2, b2, out);
}